// Round 10
// baseline (28.642 us; speedup 1.0000x reference)
//
#include <hip/hip_runtime.h>

#define DIM     64
#define NUM_E   512
#define HW      4096                 // 64*64
#define TP      128                  // pixels per workgroup
#define THREADS 256
#define NWG     1024
#define NOUT0   8388608              // 32*64*4096
#define CSCALE  256.0f               // codebook pre-scale (argmax-invariant)
#define CINV    (1.0f / 256.0f)

typedef __attribute__((ext_vector_type(4))) float f32x4;
typedef __attribute__((ext_vector_type(4))) int   i32x4;

static __device__ __forceinline__ unsigned asu(float f) {
  union { float f; unsigned u; } v; v.f = f; return v.u;
}
static __device__ __forceinline__ float asf(unsigned u) {
  union { unsigned u; float f; } v; v.u = u; return v.f;
}

// constant-selector fp8->f32 (builtin demands literal index)
#define CVT4V(dst, src)                                   \
  (dst)[0] = __builtin_amdgcn_cvt_f32_fp8((int)(src), 0); \
  (dst)[1] = __builtin_amdgcn_cvt_f32_fp8((int)(src), 1); \
  (dst)[2] = __builtin_amdgcn_cvt_f32_fp8((int)(src), 2); \
  (dst)[3] = __builtin_amdgcn_cvt_f32_fp8((int)(src), 3);

// dim mapping: d = 16*lg + 8*s + j.  frag-major layout: 16B slot
// (g,lg,col) holds dims [16lg,16lg+16) of entry e=g*16+col at int index
// (g*64 + lg*16 + col)*4 + word  -> conflict-free b128 reads.

// ---- prep: fp32 codebook -> fp8*CSCALE, frag-major, into d_ws ----
__global__ __launch_bounds__(THREADS) void vq_prep(
    const float* __restrict__ cb, int* __restrict__ pre) {
  int c  = blockIdx.x * THREADS + threadIdx.x;  // chunk id, 8192 total
  int e  = c >> 4;
  int dq = c & 15;                              // dims 4dq..4dq+3
  float4 v = reinterpret_cast<const float4*>(cb)[c];
  int d0 = __builtin_amdgcn_cvt_pk_fp8_f32(v.x * CSCALE, v.y * CSCALE, 0, false);
  d0     = __builtin_amdgcn_cvt_pk_fp8_f32(v.z * CSCALE, v.w * CSCALE, d0, true);
  pre[((((e >> 4) << 6) + ((dq >> 2) << 4) + (e & 15)) << 2) + (dq & 3)] = d0;
}

__global__ __launch_bounds__(THREADS, 4) void vq_main(
    const float* __restrict__ z_e, const int* __restrict__ pre,
    float* __restrict__ out, float* __restrict__ partial) {
  __shared__ int cbf[NUM_E * 16];           // 32 KB fp8 codebook, frag-major
  __shared__ float red_lds[THREADS / 64];

  const int t   = threadIdx.x;
  const int wg  = blockIdx.x;
  const int b   = wg >> 5;                  // 32 WGs per image
  const int hw0 = (wg & 31) * TP;
  const float* zb = z_e + (size_t)b * (DIM * HW) + hw0;
  float*       ob = out + (size_t)b * (DIM * HW) + hw0;

  const int lane = t & 63;
  const int w    = t >> 6;                  // 0..3
  const int col  = lane & 15;               // pixel within 16-block (N axis)
  const int lg   = lane >> 4;               // 0..3 (k-slice group)
  const int px0  = 32 * w + col;            // blk0 pixel (0..127)
  const int px1  = px0 + 16;                // blk1 pixel

  // ---- 1) stage pre-converted codebook: 32 KB linear copy, zero VALU ----
  {
    const i32x4* src = reinterpret_cast<const i32x4*>(pre);
    i32x4*       dst = reinterpret_cast<i32x4*>(cbf);
    #pragma unroll
    for (int i = 0; i < 8; ++i)
      dst[i * THREADS + t] = src[i * THREADS + t];
  }
  __syncthreads();

  // ---- 2) z_e loads (fp32 stays live for the loss) ----
  float zef[2][2][8];
  #pragma unroll
  for (int blk = 0; blk < 2; ++blk) {
    const int px = blk ? px1 : px0;
    #pragma unroll
    for (int s = 0; s < 2; ++s)
      #pragma unroll
      for (int j = 0; j < 8; ++j)
        zef[blk][s][j] = zb[(16 * lg + 8 * s + j) * HW + px];
  }

  // ---- 3) pack z_e fragments to fp8 (B operand) ----
  long bfr[2][2];
  #pragma unroll
  for (int blk = 0; blk < 2; ++blk)
    #pragma unroll
    for (int s = 0; s < 2; ++s) {
      const float* f = zef[blk][s];
      int lo = __builtin_amdgcn_cvt_pk_fp8_f32(f[0], f[1], 0, false);
      lo     = __builtin_amdgcn_cvt_pk_fp8_f32(f[2], f[3], lo, true);
      int hi = __builtin_amdgcn_cvt_pk_fp8_f32(f[4], f[5], 0, false);
      hi     = __builtin_amdgcn_cvt_pk_fp8_f32(f[6], f[7], hi, true);
      bfr[blk][s] = (long)(unsigned)lo | ((long)hi << 32);
    }

  // ---- 4) main loop: 32 groups, 1 b128 A-read shared by both blks ----
  float best[2] = { asf(0xFF7F0000u), asf(0xFF7F0000u) };  // ~ -3.4e38
  #pragma unroll 4
  for (int g = 0; g < 32; ++g) {
    i32x4 a = *reinterpret_cast<const i32x4*>(
        reinterpret_cast<const char*>(cbf) + (((g << 6) + (lg << 4) + col) << 4));
    long a0 = (long)(unsigned)a[0] | ((long)a[1] << 32);   // k-slice 0
    long a1 = (long)(unsigned)a[2] | ((long)a[3] << 32);   // k-slice 1
    const int ebase = g * 16 + 4 * lg;      // entry index of acc[0]
    #pragma unroll
    for (int blk = 0; blk < 2; ++blk) {
      f32x4 acc = {0.f, 0.f, 0.f, 0.f};
      acc = __builtin_amdgcn_mfma_f32_16x16x32_fp8_fp8(a0, bfr[blk][0], acc, 0, 0, 0);
      acc = __builtin_amdgcn_mfma_f32_16x16x32_fp8_fp8(a1, bfr[blk][1], acc, 0, 0, 0);
      float p0 = asf((asu(acc[0]) & ~0x1FFu) | (unsigned)(ebase + 0));
      float p1 = asf((asu(acc[1]) & ~0x1FFu) | (unsigned)(ebase + 1));
      float p2 = asf((asu(acc[2]) & ~0x1FFu) | (unsigned)(ebase + 2));
      float p3 = asf((asu(acc[3]) & ~0x1FFu) | (unsigned)(ebase + 3));
      best[blk] = fmaxf(best[blk], fmaxf(fmaxf(p0, p1), fmaxf(p2, p3)));
    }
  }

  // ---- 5) cross-lane argmax (lg groups hold disjoint entries) ----
  #pragma unroll
  for (int blk = 0; blk < 2; ++blk) {
    float bv = best[blk];
    bv = fmaxf(bv, __shfl_xor(bv, 16, 64));
    bv = fmaxf(bv, __shfl_xor(bv, 32, 64));
    best[blk] = bv;                         // every lane: packed (score|index)
  }

  // ---- 6) epilogue: gather z_q (1 b128, unscale), write, loss vs fp32 ----
  float lsum = 0.f;
  #pragma unroll
  for (int blk = 0; blk < 2; ++blk) {
    const int eb = (int)(asu(best[blk]) & 0x1FFu);
    const int px = blk ? px1 : px0;
    i32x4 q = *reinterpret_cast<const i32x4*>(
        reinterpret_cast<const char*>(cbf) +
        ((((eb >> 4) << 6) + (lg << 4) + (eb & 15)) << 4));
    #pragma unroll
    for (int s = 0; s < 2; ++s) {
      f32x4 qv0, qv1;
      CVT4V(qv0, q[2 * s]); CVT4V(qv1, q[2 * s + 1]);
      #pragma unroll
      for (int j = 0; j < 8; ++j) {
        float zq = (j < 4 ? qv0[j & 3] : qv1[j & 3]) * CINV;
        float df = zef[blk][s][j] - zq;
        lsum += df * df;
        ob[(16 * lg + 8 * s + j) * HW + px] = zq;
      }
    }
  }

  // ---- 7) loss reduction: wave shuffle -> LDS -> per-WG partial store ----
  #pragma unroll
  for (int off = 32; off; off >>= 1) lsum += __shfl_xor(lsum, off, 64);
  if (lane == 0) red_lds[w] = lsum;
  __syncthreads();
  if (t == 0) {
    float s = 0.f;
    #pragma unroll
    for (int i = 0; i < THREADS / 64; ++i) s += red_lds[i];
    partial[wg] = s;                        // no atomics anywhere
  }
}

__global__ __launch_bounds__(512, 4) void vq_finish(
    const float* __restrict__ partial, float* __restrict__ loss) {
  __shared__ float red[8];
  const int t = threadIdx.x, lane = t & 63, w = t >> 6;
  float v = partial[t] + partial[t + 512];  // NWG == 1024
  #pragma unroll
  for (int off = 32; off; off >>= 1) v += __shfl_xor(v, off, 64);
  if (lane == 0) red[w] = v;
  __syncthreads();
  if (t == 0) {
    float s = 0.f;
    #pragma unroll
    for (int i = 0; i < 8; ++i) s += red[i];
    loss[0] = s * (1.25f / (float)NOUT0);   // (1 + BETA) * mean
  }
}

extern "C" void kernel_launch(void* const* d_in, const int* in_sizes, int n_in,
                              void* d_out, int out_size, void* d_ws, size_t ws_size,
                              hipStream_t stream) {
  const float* z_e = (const float*)d_in[0];
  const float* cb  = (const float*)d_in[1];
  float* out     = (float*)d_out;
  int*   pre     = (int*)d_ws;                         // 32 KB fp8 codebook
  float* partial = (float*)((char*)d_ws + 32768);      // 1024 fp32 partials
  vq_prep<<<32, THREADS, 0, stream>>>(cb, pre);
  vq_main<<<NWG, THREADS, 0, stream>>>(z_e, pre, out, partial);
  vq_finish<<<1, 512, 0, stream>>>(partial, out + NOUT0);
}

// Round 11
// 25.794 us; speedup vs baseline: 1.1104x; 1.1104x over previous
//
#include <hip/hip_runtime.h>

#define DIM     64
#define NUM_E   512
#define HW      4096                 // 64*64
#define TP      128                  // pixels per workgroup
#define THREADS 256
#define NWG     1024
#define NOUT0   8388608              // 32*64*4096
#define CSCALE  256.0f               // codebook pre-scale (argmax-invariant)
#define CINV    (1.0f / 256.0f)

typedef __attribute__((ext_vector_type(4))) float f32x4;
typedef __attribute__((ext_vector_type(4))) int   i32x4;

static __device__ __forceinline__ unsigned asu(float f) {
  union { float f; unsigned u; } v; v.f = f; return v.u;
}
static __device__ __forceinline__ float asf(unsigned u) {
  union { unsigned u; float f; } v; v.u = u; return v.f;
}

// constant-selector fp8->f32 (builtin demands literal index)
#define CVT4V(dst, src)                                   \
  (dst)[0] = __builtin_amdgcn_cvt_f32_fp8((int)(src), 0); \
  (dst)[1] = __builtin_amdgcn_cvt_f32_fp8((int)(src), 1); \
  (dst)[2] = __builtin_amdgcn_cvt_f32_fp8((int)(src), 2); \
  (dst)[3] = __builtin_amdgcn_cvt_f32_fp8((int)(src), 3);

// dim mapping: d = 16*lg + 8*s + j.  frag-major layout: 16B slot
// (g,lg,col) holds dims [16lg,16lg+16) of entry e=g*16+col at int index
// (g*64 + lg*16 + col)*4 + word  -> conflict-free b128 reads.

__global__ __launch_bounds__(THREADS, 4) void vq_main(
    const float* __restrict__ z_e, const float* __restrict__ cb,
    float* __restrict__ out, float* __restrict__ partial) {
  __shared__ int cbf[NUM_E * 16];           // 32 KB fp8 codebook, frag-major
  __shared__ float red_lds[THREADS / 64];

  const int t   = threadIdx.x;
  const int wg  = blockIdx.x;
  const int b   = wg >> 5;                  // 32 WGs per image
  const int hw0 = (wg & 31) * TP;
  const float* zb = z_e + (size_t)b * (DIM * HW) + hw0;
  float*       ob = out + (size_t)b * (DIM * HW) + hw0;

  const int lane = t & 63;
  const int w    = t >> 6;                  // 0..3
  const int col  = lane & 15;               // pixel within 16-block (N axis)
  const int lg   = lane >> 4;               // 0..3 (k-slice group)
  const int px0  = 32 * w + col;            // blk0 pixel (0..127)
  const int px1  = px0 + 16;                // blk1 pixel

  // ---- 1) z_e loads issued first (fp32 stays live for the loss) ----
  float zef[2][2][8];
  #pragma unroll
  for (int blk = 0; blk < 2; ++blk) {
    const int px = blk ? px1 : px0;
    #pragma unroll
    for (int s = 0; s < 2; ++s)
      #pragma unroll
      for (int j = 0; j < 8; ++j)
        zef[blk][s][j] = zb[(16 * lg + 8 * s + j) * HW + px];
  }

  // ---- 2) stage codebook*256 -> fp8 LDS, frag-major (L2-hot source) ----
  const float4* cb4 = reinterpret_cast<const float4*>(cb);
  #pragma unroll
  for (int i = 0; i < 32; ++i) {
    int c  = i * THREADS + t;               // float4 chunk id, 8192 total
    int e  = c >> 4;
    int dq = c & 15;                        // dims 4dq..4dq+3
    float4 v = cb4[c];
    int d0 = __builtin_amdgcn_cvt_pk_fp8_f32(v.x * CSCALE, v.y * CSCALE, 0, false);
    d0     = __builtin_amdgcn_cvt_pk_fp8_f32(v.z * CSCALE, v.w * CSCALE, d0, true);
    cbf[((((e >> 4) << 6) + ((dq >> 2) << 4) + (e & 15)) << 2) + (dq & 3)] = d0;
  }

  // ---- 3) pack z_e fragments to fp8 (B operand) ----
  long bfr[2][2];
  #pragma unroll
  for (int blk = 0; blk < 2; ++blk)
    #pragma unroll
    for (int s = 0; s < 2; ++s) {
      const float* f = zef[blk][s];
      int lo = __builtin_amdgcn_cvt_pk_fp8_f32(f[0], f[1], 0, false);
      lo     = __builtin_amdgcn_cvt_pk_fp8_f32(f[2], f[3], lo, true);
      int hi = __builtin_amdgcn_cvt_pk_fp8_f32(f[4], f[5], 0, false);
      hi     = __builtin_amdgcn_cvt_pk_fp8_f32(f[6], f[7], hi, true);
      bfr[blk][s] = (long)(unsigned)lo | ((long)hi << 32);
    }
  __syncthreads();

  // ---- 4) main loop: 32 groups, 1 b128 A-read shared by both blks ----
  float best[2] = { asf(0xFF7F0000u), asf(0xFF7F0000u) };  // ~ -3.4e38
  #pragma unroll 4
  for (int g = 0; g < 32; ++g) {
    i32x4 a = *reinterpret_cast<const i32x4*>(
        reinterpret_cast<const char*>(cbf) + (((g << 6) + (lg << 4) + col) << 4));
    long a0 = (long)(unsigned)a[0] | ((long)a[1] << 32);   // k-slice 0
    long a1 = (long)(unsigned)a[2] | ((long)a[3] << 32);   // k-slice 1
    const int ebase = g * 16 + 4 * lg;      // entry index of acc[0]
    #pragma unroll
    for (int blk = 0; blk < 2; ++blk) {
      f32x4 acc = {0.f, 0.f, 0.f, 0.f};
      acc = __builtin_amdgcn_mfma_f32_16x16x32_fp8_fp8(a0, bfr[blk][0], acc, 0, 0, 0);
      acc = __builtin_amdgcn_mfma_f32_16x16x32_fp8_fp8(a1, bfr[blk][1], acc, 0, 0, 0);
      float p0 = asf((asu(acc[0]) & ~0x1FFu) | (unsigned)(ebase + 0));
      float p1 = asf((asu(acc[1]) & ~0x1FFu) | (unsigned)(ebase + 1));
      float p2 = asf((asu(acc[2]) & ~0x1FFu) | (unsigned)(ebase + 2));
      float p3 = asf((asu(acc[3]) & ~0x1FFu) | (unsigned)(ebase + 3));
      best[blk] = fmaxf(best[blk], fmaxf(fmaxf(p0, p1), fmaxf(p2, p3)));
    }
  }

  // ---- 5) cross-lane argmax (lg groups hold disjoint entries) ----
  #pragma unroll
  for (int blk = 0; blk < 2; ++blk) {
    float bv = best[blk];
    bv = fmaxf(bv, __shfl_xor(bv, 16, 64));
    bv = fmaxf(bv, __shfl_xor(bv, 32, 64));
    best[blk] = bv;                         // every lane: packed (score|index)
  }

  // ---- 6) epilogue: gather z_q (1 b128, unscale), write, loss vs fp32 ----
  float lsum = 0.f;
  #pragma unroll
  for (int blk = 0; blk < 2; ++blk) {
    const int eb = (int)(asu(best[blk]) & 0x1FFu);
    const int px = blk ? px1 : px0;
    i32x4 q = *reinterpret_cast<const i32x4*>(
        reinterpret_cast<const char*>(cbf) +
        ((((eb >> 4) << 6) + (lg << 4) + (eb & 15)) << 4));
    #pragma unroll
    for (int s = 0; s < 2; ++s) {
      f32x4 qv0, qv1;
      CVT4V(qv0, q[2 * s]); CVT4V(qv1, q[2 * s + 1]);
      #pragma unroll
      for (int j = 0; j < 8; ++j) {
        float zq = (j < 4 ? qv0[j & 3] : qv1[j & 3]) * CINV;
        float df = zef[blk][s][j] - zq;
        lsum += df * df;
        ob[(16 * lg + 8 * s + j) * HW + px] = zq;
      }
    }
  }

  // ---- 7) loss reduction: wave shuffle -> LDS -> per-WG partial store ----
  #pragma unroll
  for (int off = 32; off; off >>= 1) lsum += __shfl_xor(lsum, off, 64);
  if (lane == 0) red_lds[w] = lsum;
  __syncthreads();
  if (t == 0) {
    float s = 0.f;
    #pragma unroll
    for (int i = 0; i < THREADS / 64; ++i) s += red_lds[i];
    partial[wg] = s;                        // no atomics anywhere
  }
}

__global__ __launch_bounds__(512, 4) void vq_finish(
    const float* __restrict__ partial, float* __restrict__ loss) {
  __shared__ float red[8];
  const int t = threadIdx.x, lane = t & 63, w = t >> 6;
  float v = partial[t] + partial[t + 512];  // NWG == 1024
  #pragma unroll
  for (int off = 32; off; off >>= 1) v += __shfl_xor(v, off, 64);
  if (lane == 0) red[w] = v;
  __syncthreads();
  if (t == 0) {
    float s = 0.f;
    #pragma unroll
    for (int i = 0; i < 8; ++i) s += red[i];
    loss[0] = s * (1.25f / (float)NOUT0);   // (1 + BETA) * mean
  }
}

extern "C" void kernel_launch(void* const* d_in, const int* in_sizes, int n_in,
                              void* d_out, int out_size, void* d_ws, size_t ws_size,
                              hipStream_t stream) {
  const float* z_e = (const float*)d_in[0];
  const float* cb  = (const float*)d_in[1];
  float* out     = (float*)d_out;
  float* partial = (float*)d_ws;            // 1024 fp32 partials
  vq_main<<<NWG, THREADS, 0, stream>>>(z_e, cb, out, partial);
  vq_finish<<<1, 512, 0, stream>>>(partial, out + NOUT0);
}